// Round 1
// baseline (130.571 us; speedup 1.0000x reference)
//
#include <hip/hip_runtime.h>
#include <hip/hip_bf16.h>
#include <stdint.h>

#define UNITS 1024
#define IDIM  512
#define BATCH 2048
#define KTOT  1536   // UNITS + IDIM
#define NGATE 4096   // 4*UNITS

#define BM 128
#define BU 32
#define BK 64

typedef short bf16x8 __attribute__((ext_vector_type(8)));   // 8 bf16 in 4 VGPRs
typedef float f32x4  __attribute__((ext_vector_type(4)));

#define AS3(p) ((__attribute__((address_space(3))) void*)(p))
#define AS1(p) ((const __attribute__((address_space(1))) void*)(p))

// ---------------------------------------------------------------------------
// Phase 1a: A = concat([h_tm1, inputs], axis=-1) cast to bf16, row-major K-contig
// ---------------------------------------------------------------------------
struct alignas(8) bh4 { __hip_bfloat16 a, b, c, d; };

__global__ __launch_bounds__(256) void cast_concat_a(
    const float* __restrict__ x, const float* __restrict__ h,
    __hip_bfloat16* __restrict__ A) {
  int tid = blockIdx.x * 256 + threadIdx.x;   // one float4 per thread
  int r  = tid / (KTOT / 4);
  int c4 = tid % (KTOT / 4);
  int k  = c4 * 4;
  const float* src = (k < UNITS) ? (h + (size_t)r * UNITS + k)
                                 : (x + (size_t)r * IDIM + (k - UNITS));
  float4 v = *(const float4*)src;
  bh4 o = { __float2bfloat16(v.x), __float2bfloat16(v.y),
            __float2bfloat16(v.z), __float2bfloat16(v.w) };
  *(bh4*)(A + (size_t)r * KTOT + k) = o;
}

// ---------------------------------------------------------------------------
// Phase 1b: Wt[n][k] = bf16(W[k][n])  (LDS tile transpose, 32x33 pad)
// ---------------------------------------------------------------------------
__global__ __launch_bounds__(256) void transpose_w(
    const float* __restrict__ W, __hip_bfloat16* __restrict__ Wt) {
  __shared__ float tile[32][33];
  int n0 = blockIdx.x * 32;
  int k0 = blockIdx.y * 32;
  int tx = threadIdx.x & 31;
  int ty = threadIdx.x >> 5;   // 0..7
#pragma unroll
  for (int r = 0; r < 32; r += 8)
    tile[ty + r][tx] = W[(size_t)(k0 + ty + r) * NGATE + n0 + tx];
  __syncthreads();
#pragma unroll
  for (int r = 0; r < 32; r += 8)
    Wt[(size_t)(n0 + ty + r) * KTOT + k0 + tx] = __float2bfloat16(tile[tx][ty + r]);
}

// ---------------------------------------------------------------------------
// Phase 2: fused GEMM + LSTM gates.
// Block: 128 batch rows x 32 units, all 4 gates (virtual N = 128 cols:
//   n = g*32 + u_local, col-tile j = g*2 + uh, uh in {0,1}).
// Wave w: rows [32w, 32w+32) x all 128 virtual cols -> acc[2][8] of 16x16.
// LDS: A tile [128][64] bf16 (16 KB) + B tile [128][64] bf16 (16 KB).
// 16-byte chunks XOR-swizzled: chunk(row,k8) = row*8 + (k8 ^ (row&7)) so
// ds_read_b128 fragment loads are 2 lanes/bank (free), while global_load_lds
// keeps its mandatory dest = base + lane*16 (we permute the *source* per lane).
// ---------------------------------------------------------------------------
__global__ __launch_bounds__(256) void lstm_gemm(
    const __hip_bfloat16* __restrict__ A,
    const __hip_bfloat16* __restrict__ Wt,
    const float* __restrict__ c_tm1,
    float* __restrict__ out) {
  __shared__ __attribute__((aligned(128))) char ldsc[2 * 128 * BK * 2];  // 32 KB

  const int tid  = threadIdx.x;
  const int w    = tid >> 6;       // wave 0..3 (wave-uniform)
  const int lane = tid & 63;
  const int quad = lane >> 4;
  const int m16  = lane & 15;

  const int mb = blockIdx.x >> 5;  // 0..15
  const int ub = blockIdx.x & 31;  // 0..31
  const int m0 = mb * BM;
  const int u0 = ub * BU;

  f32x4 acc[2][8];
#pragma unroll
  for (int i = 0; i < 2; ++i)
#pragma unroll
    for (int j = 0; j < 8; ++j) {
      f32x4 z = {0.f, 0.f, 0.f, 0.f};
      acc[i][j] = z;
    }

  for (int kt = 0; kt < KTOT; kt += BK) {
    // ---- stage: 32 global_load_lds_dwordx4 total, 8 per wave ----
#pragma unroll
    for (int s = 0; s < 8; ++s) {
      const int q     = s * 4 + w;          // wave-uniform
      const int rbase = (q & 15) * 8;       // wave-uniform
      const int lr    = rbase + (lane >> 3);
      const int k8    = (lane & 7) ^ (lr & 7);   // source-side swizzle
      const __hip_bfloat16* src;
      if (q < 16) {  // A tile rows
        src = A + (size_t)(m0 + lr) * KTOT + kt + k8 * 8;
      } else {       // B tile: virtual row lr -> Wt row g*UNITS + u0 + ulocal
        const int row = ((lr >> 5) * UNITS) + u0 + (lr & 31);
        src = Wt + (size_t)row * KTOT + kt + k8 * 8;
      }
      char* dst = ldsc + (q < 16 ? 0 : 16384) + rbase * 128;  // wave-uniform base
      __builtin_amdgcn_global_load_lds(AS1(src), AS3(dst), 16, 0, 0);
    }
    __syncthreads();

    // ---- compute: 2 K-steps x 16 MFMAs ----
#pragma unroll
    for (int t = 0; t < 2; ++t) {
      bf16x8 a[2], b[8];
#pragma unroll
      for (int i = 0; i < 2; ++i) {
        const int row   = 32 * w + 16 * i + m16;
        const int k8    = t * 4 + quad;
        const int chunk = row * 8 + (k8 ^ (row & 7));
        a[i] = *(const bf16x8*)(ldsc + chunk * 16);
      }
#pragma unroll
      for (int j = 0; j < 8; ++j) {
        const int row   = 16 * j + m16;
        const int k8    = t * 4 + quad;
        const int chunk = row * 8 + (k8 ^ (row & 7));
        b[j] = *(const bf16x8*)(ldsc + 16384 + chunk * 16);
      }
#pragma unroll
      for (int j = 0; j < 8; ++j)
#pragma unroll
        for (int i = 0; i < 2; ++i)
          acc[i][j] = __builtin_amdgcn_mfma_f32_16x16x32_bf16(a[i], b[j], acc[i][j], 0, 0, 0);
    }
    __syncthreads();
  }

  // ---- fused LSTM epilogue (register-local: all 4 gates in-lane) ----
#pragma unroll
  for (int i = 0; i < 2; ++i)
#pragma unroll
    for (int uh = 0; uh < 2; ++uh)
#pragma unroll
      for (int reg = 0; reg < 4; ++reg) {
        const int r = m0 + 32 * w + 16 * i + quad * 4 + reg;
        const int u = u0 + uh * 16 + m16;
        const float z0 = acc[i][0 + uh][reg];   // gate i  (j = g*2+uh)
        const float z1 = acc[i][2 + uh][reg];   // gate f
        const float z2 = acc[i][4 + uh][reg];   // c_tilde
        const float z3 = acc[i][6 + uh][reg];   // gate o
        const float ig = 1.f / (1.f + __expf(-z0));
        const float fg = 1.f / (1.f + __expf(-z1));
        const float ct = 1.f - 2.f / (__expf(2.f * z2) + 1.f);   // tanh, inf-safe
        const float og = 1.f / (1.f + __expf(-z3));
        const float cc = fg * c_tm1[(size_t)r * UNITS + u] + ig * ct;
        const float hh = og * (1.f - 2.f / (__expf(2.f * cc) + 1.f));
        out[(size_t)r * UNITS + u] = hh;
        out[(size_t)BATCH * UNITS + (size_t)r * UNITS + u] = cc;
      }
}

// ---------------------------------------------------------------------------
// Fallback (only if d_ws is too small): naive fp32, correct but slow.
// ---------------------------------------------------------------------------
__global__ __launch_bounds__(256) void lstm_naive(
    const float* __restrict__ x, const float* __restrict__ h,
    const float* __restrict__ c_tm1, const float* __restrict__ W,
    float* __restrict__ out) {
  int idx = blockIdx.x * 256 + threadIdx.x;   // over BATCH*UNITS
  int r = idx / UNITS;
  int u = idx % UNITS;
  float z[4] = {0.f, 0.f, 0.f, 0.f};
  for (int k = 0; k < KTOT; ++k) {
    float a = (k < UNITS) ? h[(size_t)r * UNITS + k] : x[(size_t)r * IDIM + k - UNITS];
#pragma unroll
    for (int g = 0; g < 4; ++g)
      z[g] += a * W[(size_t)k * NGATE + g * UNITS + u];
  }
  float ig = 1.f / (1.f + __expf(-z[0]));
  float fg = 1.f / (1.f + __expf(-z[1]));
  float ct = 1.f - 2.f / (__expf(2.f * z[2]) + 1.f);
  float og = 1.f / (1.f + __expf(-z[3]));
  float cc = fg * c_tm1[(size_t)r * UNITS + u] + ig * ct;
  float hh = og * (1.f - 2.f / (__expf(2.f * cc) + 1.f));
  out[(size_t)r * UNITS + u] = hh;
  out[(size_t)BATCH * UNITS + (size_t)r * UNITS + u] = cc;
}

extern "C" void kernel_launch(void* const* d_in, const int* in_sizes, int n_in,
                              void* d_out, int out_size, void* d_ws, size_t ws_size,
                              hipStream_t stream) {
  const float* x = (const float*)d_in[0];   // [2048][512]
  const float* h = (const float*)d_in[1];   // [2048][1024]
  const float* c = (const float*)d_in[2];   // [2048][1024]
  const float* W = (const float*)d_in[3];   // [1536][4096]
  float* out = (float*)d_out;               // h then c, 2 x [2048][1024]

  const size_t needA  = (size_t)BATCH * KTOT * sizeof(__hip_bfloat16);  // 6.29 MB
  const size_t needWt = (size_t)NGATE * KTOT * sizeof(__hip_bfloat16);  // 12.58 MB
  if (ws_size < needA + needWt) {
    // Insurance path; should not trigger with a normally-sized workspace.
    hipLaunchKernelGGL(lstm_naive, dim3((BATCH * UNITS) / 256), dim3(256), 0, stream,
                       x, h, c, W, out);
    return;
  }

  __hip_bfloat16* A  = (__hip_bfloat16*)d_ws;
  __hip_bfloat16* Wt = (__hip_bfloat16*)((char*)d_ws + needA);

  hipLaunchKernelGGL(cast_concat_a, dim3((BATCH * (KTOT / 4)) / 256), dim3(256), 0,
                     stream, x, h, A);
  hipLaunchKernelGGL(transpose_w, dim3(NGATE / 32, KTOT / 32), dim3(256), 0,
                     stream, W, Wt);
  hipLaunchKernelGGL(lstm_gemm, dim3((BATCH / BM) * (UNITS / BU)), dim3(256), 0,
                     stream, A, Wt, c, out);
}

// Round 2
// 126.081 us; speedup vs baseline: 1.0356x; 1.0356x over previous
//
#include <hip/hip_runtime.h>
#include <hip/hip_bf16.h>
#include <stdint.h>

#define UNITS 1024
#define IDIM  512
#define BATCH 2048
#define KTOT  1536   // UNITS + IDIM
#define NGATE 4096   // 4*UNITS
#define BK    64

typedef short bf16x8 __attribute__((ext_vector_type(8)));   // 8 bf16 = 4 VGPRs
typedef float f32x4  __attribute__((ext_vector_type(4)));

#define AS3(p) ((__attribute__((address_space(3))) void*)(p))
#define AS1(p) ((const __attribute__((address_space(1))) void*)(p))

union P8 { bf16x8 v; __hip_bfloat16 e[8]; };

// ---------------------------------------------------------------------------
// prep: blocks [0,1536) cast-concat A = bf16(concat[h,x]); blocks [1536,4608)
// transpose W fp32 [1536][4096] -> Wt bf16 [4096][1536].
// Transpose tile: 64 k x 32 n per block, LDS [32][65] (pad 65 -> 2-way banks,
// free per m136), Wt stores are 16B-wide and contiguous per n-row.
// ---------------------------------------------------------------------------
#define NBLK_A 1536
#define NBLK_T 3072

__global__ __launch_bounds__(256) void prep(
    const float* __restrict__ x, const float* __restrict__ h,
    const float* __restrict__ W,
    __hip_bfloat16* __restrict__ A, __hip_bfloat16* __restrict__ Wt) {
  __shared__ float tile[32][65];
  const int tid = threadIdx.x;
  if (blockIdx.x < NBLK_A) {
    const int id = blockIdx.x * 256 + tid;
    const int r = id / (KTOT / 8);
    const int k = (id % (KTOT / 8)) * 8;
    const float* src = (k < UNITS) ? h + (size_t)r * UNITS + k
                                   : x + (size_t)r * IDIM + (k - UNITS);
    const float4 v0 = ((const float4*)src)[0];
    const float4 v1 = ((const float4*)src)[1];
    P8 o;
    o.e[0] = __float2bfloat16(v0.x); o.e[1] = __float2bfloat16(v0.y);
    o.e[2] = __float2bfloat16(v0.z); o.e[3] = __float2bfloat16(v0.w);
    o.e[4] = __float2bfloat16(v1.x); o.e[5] = __float2bfloat16(v1.y);
    o.e[6] = __float2bfloat16(v1.z); o.e[7] = __float2bfloat16(v1.w);
    *(bf16x8*)(A + (size_t)r * KTOT + k) = o.v;
  } else {
    const int b  = blockIdx.x - NBLK_A;   // 0..3071
    const int kb = b >> 7;                // 0..23  (1536/64)
    const int nb = b & 127;               // 0..127 (4096/32)
    const int k0 = kb * 64, n0 = nb * 32;
    // phase 1: coalesced float4 reads of W rows -> LDS transposed
    const int n4 = (tid & 7) * 4;
    const int kk = tid >> 3;              // 0..31
#pragma unroll
    for (int rr = 0; rr < 64; rr += 32) {
      const float4 v = *(const float4*)(W + (size_t)(k0 + kk + rr) * NGATE + n0 + n4);
      tile[n4 + 0][kk + rr] = v.x; tile[n4 + 1][kk + rr] = v.y;
      tile[n4 + 2][kk + rr] = v.z; tile[n4 + 3][kk + rr] = v.w;
    }
    __syncthreads();
    // phase 2: 8 k-consecutive floats per thread -> one 16B bf16 store
    const int n  = tid >> 3;              // 0..31
    const int k8 = (tid & 7) * 8;         // 0..56
    P8 o;
#pragma unroll
    for (int j = 0; j < 8; ++j) o.e[j] = __float2bfloat16(tile[n][k8 + j]);
    *(bf16x8*)(Wt + (size_t)(n0 + n) * KTOT + k0 + k8) = o.v;
  }
}

// ---------------------------------------------------------------------------
// GEMM + fused LSTM gates. Grid 1024 blocks (4/CU): block = 64 batch rows x
// 32 units x 4 gates (128 virtual cols). 4 waves tile 2x2: wr=row half,
// wc=unit half -- each wave holds ALL 4 gates for its 16 units, so the
// epilogue is register-local. acc[2][4] 16x16 tiles (32 VGPR).
// LDS: A 64x64 bf16 (8KB) @0, B 128x64 bf16 (16KB) @8192. 16B chunks
// XOR-swizzled chunk(row,k8)=row*8+(k8^(row&7)) -> 2 lanes/bank (free).
// Staging: 24 global_load_lds_dwordx4 per block per iter, pointers
// precomputed and bumped by BK elements/iter (no per-iter addr math).
// XCD swizzle: ub from low blockIdx bits so each XCD's L2 keeps 4 B-tiles
// (~1.6MB) resident; consecutive slots share mb so A-tiles reuse in L2.
// ---------------------------------------------------------------------------
__global__ __launch_bounds__(256, 4) void lstm_gemm(
    const __hip_bfloat16* __restrict__ A,
    const __hip_bfloat16* __restrict__ Wt,
    const float* __restrict__ c_tm1,
    float* __restrict__ out) {
  __shared__ __attribute__((aligned(128))) char lds[24576];

  const int tid  = threadIdx.x;
  const int w    = tid >> 6;     // wave 0..3 (uniform)
  const int lane = tid & 63;
  const int quad = lane >> 4;
  const int m16  = lane & 15;
  const int wr   = w >> 1;       // row half
  const int wc   = w & 1;        // unit half

  const int bi = blockIdx.x;
  const int ub = ((bi & 7) << 2) | ((bi >> 3) & 3);   // 0..31
  const int mb = bi >> 5;                             // 0..31
  const int m0 = mb * 64;
  const int u0 = ub * 32;

  // precompute staging sources (per-lane) and LDS dests (wave-uniform)
  const __hip_bfloat16* ptr[6];
  int dstoff[6];
#pragma unroll
  for (int s = 0; s < 6; ++s) {
    const int q = s * 4 + w;     // 0..23, wave-uniform selector
    if (q < 8) {                 // A tile: 8 wave-instr = 512 chunks
      const int ci  = q * 64 + lane;
      const int row = ci >> 3;
      const int k8  = (ci & 7) ^ (row & 7);
      ptr[s]    = A + (size_t)(m0 + row) * KTOT + k8 * 8;
      dstoff[s] = q * 1024;
    } else {                     // B tile: 16 wave-instr = 1024 chunks
      const int ci   = (q - 8) * 64 + lane;
      const int vr   = ci >> 3;  // virtual col 0..127: gate=vr>>5, ul=vr&31
      const int k8   = (ci & 7) ^ (vr & 7);
      const int wrow = ((vr >> 5) << 10) + u0 + (vr & 31);
      ptr[s]    = Wt + (size_t)wrow * KTOT + k8 * 8;
      dstoff[s] = 8192 + (q - 8) * 1024;
    }
  }

  f32x4 acc[2][4];
#pragma unroll
  for (int i = 0; i < 2; ++i)
#pragma unroll
    for (int g = 0; g < 4; ++g) {
      f32x4 z = {0.f, 0.f, 0.f, 0.f};
      acc[i][g] = z;
    }

  for (int kt = 0; kt < KTOT; kt += BK) {
#pragma unroll
    for (int s = 0; s < 6; ++s) {
      __builtin_amdgcn_global_load_lds(AS1(ptr[s]), AS3(lds + dstoff[s]), 16, 0, 0);
      ptr[s] += BK;
    }
    __syncthreads();

#pragma unroll
    for (int t = 0; t < 2; ++t) {
      bf16x8 a[2], b[4];
#pragma unroll
      for (int i = 0; i < 2; ++i) {
        const int row  = 32 * wr + 16 * i + m16;
        const int slot = (t * 4 + quad) ^ (row & 7);
        a[i] = *(const bf16x8*)(lds + (row * 8 + slot) * 16);
      }
#pragma unroll
      for (int g = 0; g < 4; ++g) {
        const int vr   = g * 32 + wc * 16 + m16;
        const int slot = (t * 4 + quad) ^ (vr & 7);
        b[g] = *(const bf16x8*)(lds + 8192 + (vr * 8 + slot) * 16);
      }
#pragma unroll
      for (int g = 0; g < 4; ++g)
#pragma unroll
        for (int i = 0; i < 2; ++i)
          acc[i][g] = __builtin_amdgcn_mfma_f32_16x16x32_bf16(a[i], b[g], acc[i][g], 0, 0, 0);
    }
    __syncthreads();
  }

  // fused LSTM epilogue -- all 4 gates live in-lane
#pragma unroll
  for (int i = 0; i < 2; ++i)
#pragma unroll
    for (int reg = 0; reg < 4; ++reg) {
      const int r = m0 + 32 * wr + 16 * i + quad * 4 + reg;
      const int u = u0 + wc * 16 + m16;
      const float z0 = acc[i][0][reg];   // gate i
      const float z1 = acc[i][1][reg];   // gate f
      const float z2 = acc[i][2][reg];   // c_tilde
      const float z3 = acc[i][3][reg];   // gate o
      const float ig = 1.f / (1.f + __expf(-z0));
      const float fg = 1.f / (1.f + __expf(-z1));
      const float ct = 1.f - 2.f / (__expf(2.f * z2) + 1.f);   // tanh, inf-safe
      const float og = 1.f / (1.f + __expf(-z3));
      const float cc = fg * c_tm1[(size_t)r * UNITS + u] + ig * ct;
      const float hh = og * (1.f - 2.f / (__expf(2.f * cc) + 1.f));
      out[(size_t)r * UNITS + u] = hh;
      out[(size_t)BATCH * UNITS + (size_t)r * UNITS + u] = cc;
    }
}

// ---------------------------------------------------------------------------
// Fallback (only if d_ws too small): naive fp32, correct but slow.
// ---------------------------------------------------------------------------
__global__ __launch_bounds__(256) void lstm_naive(
    const float* __restrict__ x, const float* __restrict__ h,
    const float* __restrict__ c_tm1, const float* __restrict__ W,
    float* __restrict__ out) {
  int idx = blockIdx.x * 256 + threadIdx.x;
  int r = idx / UNITS;
  int u = idx % UNITS;
  float z[4] = {0.f, 0.f, 0.f, 0.f};
  for (int k = 0; k < KTOT; ++k) {
    float a = (k < UNITS) ? h[(size_t)r * UNITS + k] : x[(size_t)r * IDIM + k - UNITS];
#pragma unroll
    for (int g = 0; g < 4; ++g)
      z[g] += a * W[(size_t)k * NGATE + g * UNITS + u];
  }
  float ig = 1.f / (1.f + __expf(-z[0]));
  float fg = 1.f / (1.f + __expf(-z[1]));
  float ct = 1.f - 2.f / (__expf(2.f * z[2]) + 1.f);
  float og = 1.f / (1.f + __expf(-z[3]));
  float cc = fg * c_tm1[(size_t)r * UNITS + u] + ig * ct;
  float hh = og * (1.f - 2.f / (__expf(2.f * cc) + 1.f));
  out[(size_t)r * UNITS + u] = hh;
  out[(size_t)BATCH * UNITS + (size_t)r * UNITS + u] = cc;
}

extern "C" void kernel_launch(void* const* d_in, const int* in_sizes, int n_in,
                              void* d_out, int out_size, void* d_ws, size_t ws_size,
                              hipStream_t stream) {
  const float* x = (const float*)d_in[0];   // [2048][512]
  const float* h = (const float*)d_in[1];   // [2048][1024]
  const float* c = (const float*)d_in[2];   // [2048][1024]
  const float* W = (const float*)d_in[3];   // [1536][4096]
  float* out = (float*)d_out;               // h then c, 2 x [2048][1024]

  const size_t needA  = (size_t)BATCH * KTOT * sizeof(__hip_bfloat16);  // 6.29 MB
  const size_t needWt = (size_t)NGATE * KTOT * sizeof(__hip_bfloat16);  // 12.58 MB
  if (ws_size < needA + needWt) {
    hipLaunchKernelGGL(lstm_naive, dim3((BATCH * UNITS) / 256), dim3(256), 0, stream,
                       x, h, c, W, out);
    return;
  }

  __hip_bfloat16* A  = (__hip_bfloat16*)d_ws;
  __hip_bfloat16* Wt = (__hip_bfloat16*)((char*)d_ws + needA);

  hipLaunchKernelGGL(prep, dim3(NBLK_A + NBLK_T), dim3(256), 0, stream, x, h, W, A, Wt);
  hipLaunchKernelGGL(lstm_gemm, dim3(1024), dim3(256), 0, stream, A, Wt, c, out);
}